// Round 15
// baseline (97.410 us; speedup 1.0000x reference)
//
#include <hip/hip_runtime.h>
#include <hip/hip_fp16.h>

#define Bn   4
#define CINc 64
#define COUTc 64
#define Hn   128
#define Wn   128
#define HW   (Hn * Wn)
#define KKc  9
#define NOFF 18

// padded window geometry: 8-px group = 1040 B (1024 + 16 pad), row = 16 groups
#define GRP  1040
#define ROWB (16 * GRP)                     // 16640 B per window row
#define WREG (5 * ROWB)                     // 83200 B, weight region offset

typedef short bf16x8 __attribute__((ext_vector_type(8)));
typedef float f32x4  __attribute__((ext_vector_type(4)));
typedef float f32x2  __attribute__((ext_vector_type(2)));

__device__ inline unsigned short f2bf(float f) {   // RNE fp32 -> bf16
    unsigned int u = __float_as_uint(f);
    return (unsigned short)((u + 0x7fffu + ((u >> 16) & 1u)) >> 16);
}

__device__ inline void dma16(const void* g, void* l) {
#if __has_builtin(__builtin_amdgcn_global_load_lds)
    __builtin_amdgcn_global_load_lds(
        (__attribute__((address_space(1))) void*)(g),
        (__attribute__((address_space(3))) void*)(l), 16, 0, 0);
#else
    *(uint4*)l = *(const uint4*)g;
#endif
}

// ---------------------------------------------------------------------------
// prep_all v22: transpose retiled to 256 FAT blocks (64ch x 256px = 2 rows).
// Theory: prep's ~24us (vs ~4us traffic ideal) is discontiguity-bound —
// old tiling read 256B chunks at 64KB stride (65k chunk-events). New tiling
// reads 1KB chunks (16 lanes x float4 contiguous), 4x fewer events. bf16
// conversion moved to LDS-write time; xt output layout IDENTICAL to v20.
// Weight-table blocks (216) unchanged, appended at gb>=256.
// ---------------------------------------------------------------------------
__global__ __launch_bounds__(256) void prep_all(
        const float* __restrict__ x, unsigned short* __restrict__ xt,
        const float* __restrict__ w_off, const float* __restrict__ w_def,
        unsigned short* __restrict__ wkb_sw, unsigned short* __restrict__ wob_sw) {
    int gb = blockIdx.x;
    int t  = threadIdx.x;
    if (gb < 256) {
        __shared__ unsigned short s16[64][264];     // 33792 B, 8-elem pad
        int b  = gb >> 6;                   // 0..3
        int hp = gb & 63;                   // row-pair: rows 2hp, 2hp+1
        int w64 = t & 15, cg = t >> 4;      // 16 lanes x float4 = 1KB/chan

        const float* xb = x + (size_t)b * CINc * HW + (size_t)hp * 256;
        #pragma unroll
        for (int cc = 0; cc < 4; ++cc) {
            int c = cg * 4 + cc;
            #pragma unroll
            for (int j = 0; j < 4; ++j) {
                int px = j * 64 + w64 * 4;
                float4 v = *(const float4*)(xb + (size_t)c * HW + px);
                s16[c][px]     = f2bf(v.x);
                s16[c][px + 1] = f2bf(v.y);
                s16[c][px + 2] = f2bf(v.z);
                s16[c][px + 3] = f2bf(v.w);
            }
        }
        __syncthreads();

        int cpair = t & 31, pxg = t >> 5;   // 8 px-groups x 32 px
        unsigned* xtp = (unsigned*)xt;
        size_t gbase = (size_t)b * HW + (size_t)hp * 256;
        #pragma unroll
        for (int i = 0; i < 16; ++i) {
            int px = pxg * 32 + i * 2;
            unsigned a  = *(const unsigned*)&s16[cpair * 2][px];
            unsigned bl = *(const unsigned*)&s16[cpair * 2 + 1][px];
            unsigned d0 = (a & 0xFFFFu) | (bl << 16);
            unsigned d1 = (a >> 16) | (bl & 0xFFFF0000u);
            xtp[(gbase + px) * 32 + cpair]     = d0;
            xtp[(gbase + px + 1) * 32 + cpair] = d1;
        }
        return;
    }
    int idx = (gb - 256) * 256 + t;
    if (idx < 36864) {
        int j = idx & 7, l = (idx >> 3) & 63, s = idx >> 9;
        int k = s >> 3, kc = (s >> 2) & 1, ot = s & 3;
        int l15 = l & 15, quad = l >> 4;
        int o = ot * 16 + l15, c = kc * 32 + quad * 8 + j;
        wkb_sw[idx] = f2bf(w_def[((size_t)o * 64 + c) * 9 + k]);
    }
    int i2 = idx - 36864;
    if (i2 >= 0 && i2 < 18432) {
        int j = i2 & 7, l = (i2 >> 3) & 63, s = i2 >> 9;
        int tt = s >> 2, kc = (s >> 1) & 1, mt = s & 1;
        int l15 = l & 15, quad = l >> 4;
        int m = mt * 16 + l15, c = kc * 32 + quad * 8 + j;
        unsigned short v = 0;
        if (m < NOFF) v = f2bf(w_off[((size_t)m * 64 + c) * 9 + tt]);
        wob_sw[i2] = v;
    }
}

// ---------------------------------------------------------------------------
// Fused deformable conv v22 = v20 (bf16, best measured) + PADDED window.
// v21's counters showed SQ_LDS_BANK_CONFLICT=1.13M: with 128B pixel stride,
// bank group = swizzle slot only -> 8 lanes per 4-bank group per b128 read.
// Group stride 1040 adds 4*g mod 32 bank phase; slot XOR + group phase
// balances all 32 banks (per-quad each group hit 2x = free, m136).
// Window: [0, 83200) padded rows; weights at [83200, +73728) = 156928 total.
// Datapath, barriers, fallback: v20-verbatim (f16 experiment reverted).
// ---------------------------------------------------------------------------

#define BFBUILD(C, kc, BF, W0, W1, W2, W3)                                   \
    do {                                                                     \
        const unsigned* t0 = (const unsigned*)&(C)[(kc) * 4 + 0];            \
        const unsigned* t1 = (const unsigned*)&(C)[(kc) * 4 + 1];            \
        const unsigned* b0 = (const unsigned*)&(C)[(kc) * 4 + 2];            \
        const unsigned* b1 = (const unsigned*)&(C)[(kc) * 4 + 3];            \
        _Pragma("unroll")                                                    \
        for (int jd = 0; jd < 4; ++jd) {                                     \
            f32x2 t0p = {__uint_as_float(t0[jd] << 16),                      \
                         __uint_as_float(t0[jd] & 0xFFFF0000u)};             \
            f32x2 t1p = {__uint_as_float(t1[jd] << 16),                      \
                         __uint_as_float(t1[jd] & 0xFFFF0000u)};             \
            f32x2 b0p = {__uint_as_float(b0[jd] << 16),                      \
                         __uint_as_float(b0[jd] & 0xFFFF0000u)};             \
            f32x2 b1p = {__uint_as_float(b1[jd] << 16),                      \
                         __uint_as_float(b1[jd] & 0xFFFF0000u)};             \
            f32x2 vv = t0p * (W0) + t1p * (W1) + b0p * (W2) + b1p * (W3);    \
            unsigned pk;                                                     \
            asm("v_cvt_pk_bf16_f32 %0, %1, %2"                               \
                : "=v"(pk) : "v"(vv.x), "v"(vv.y));                          \
            (BF).u[jd] = pk;                                                 \
        }                                                                    \
    } while (0)

#define TAP(k)                                                               \
    do {                                                                     \
        const uint4* C = R[(k) & 1];                                         \
        union { unsigned u; __half2 hv; } c01, c23;                          \
        c01.u = pw01[(k)]; c23.u = pw23[(k)];                                \
        float W0 = __low2float(c01.hv), W1 = __high2float(c01.hv);           \
        float W2 = __low2float(c23.hv), W3 = __high2float(c23.hv);           \
        union { bf16x8 v; unsigned u[4]; } bfa, bfb;                         \
        BFBUILD(C, 0, bfa, W0, W1, W2, W3);                                  \
        BFBUILD(C, 1, bfb, W0, W1, W2, W3);                                  \
        _Pragma("unroll")                                                    \
        for (int ot = 0; ot < 4; ++ot) {                                     \
            bf16x8 af0 = s_wv[(((k) * 2 + 0) * 4 + ot) * 64 + lane];         \
            acc[ot] = __builtin_amdgcn_mfma_f32_16x16x32_bf16(               \
                af0, bfa.v, acc[ot], 0, 0, 0);                               \
            bf16x8 af1 = s_wv[(((k) * 2 + 1) * 4 + ot) * 64 + lane];         \
            acc[ot] = __builtin_amdgcn_mfma_f32_16x16x32_bf16(               \
                af1, bfb.v, acc[ot], 0, 0, 0);                               \
        }                                                                    \
    } while (0)

// global-path fetch (v13 verbatim) — fallback when window exceeded
#define FETCH_G(kk, st)                                              \
    do {                                                             \
        unsigned ad_ = ad[kk];                                       \
        unsigned xc_ = ad_ >> 16;                                    \
        unsigned at_ = (((ad_ & 255u) << 7) + xc_) << 6;             \
        unsigned ab_ = ((((ad_ >> 8) & 255u) << 7) + xc_) << 6;      \
        R[st][0] = *(const uint4*)(xtb + at_ + co0);                 \
        R[st][1] = *(const uint4*)(xtb + at_ + 64 + co0);            \
        R[st][2] = *(const uint4*)(xtb + ab_ + co0);                 \
        R[st][3] = *(const uint4*)(xtb + ab_ + 64 + co0);            \
        R[st][4] = *(const uint4*)(xtb + at_ + co1);                 \
        R[st][5] = *(const uint4*)(xtb + at_ + 64 + co1);            \
        R[st][6] = *(const uint4*)(xtb + ab_ + co1);                 \
        R[st][7] = *(const uint4*)(xtb + ab_ + 64 + co1);            \
    } while (0)

// LDS-window fetch, padded addressing: pixel x at row r lives at
// r*ROWB + (x>>3)*GRP + (x&7)*128, chunk j at + (j^(x&7))*16.
#define FETCH_L(kk, st)                                              \
    do {                                                             \
        unsigned ad_ = ad[kk];                                       \
        int x0_ = (int)(ad_ >> 16);                                  \
        int x1_ = x0_ + 1;                                           \
        int rt_ = ((int)(ad_ & 255u) - h + 2) * ROWB;                \
        int rb_ = ((int)((ad_ >> 8) & 255u) - h + 2) * ROWB;         \
        int a0_ = (x0_ >> 3) * GRP + (x0_ & 7) * 128;                \
        int a1_ = (x1_ >> 3) * GRP + (x1_ & 7) * 128;                \
        int j0  = (quad ^ (x0_ & 7)) << 4;                           \
        int j1  = (quad ^ (x1_ & 7)) << 4;                           \
        int j0b = ((4 + quad) ^ (x0_ & 7)) << 4;                     \
        int j1b = ((4 + quad) ^ (x1_ & 7)) << 4;                     \
        R[st][0] = *(const uint4*)(s_mem + rt_ + a0_ + j0);          \
        R[st][1] = *(const uint4*)(s_mem + rt_ + a1_ + j1);          \
        R[st][2] = *(const uint4*)(s_mem + rb_ + a0_ + j0);          \
        R[st][3] = *(const uint4*)(s_mem + rb_ + a1_ + j1);          \
        R[st][4] = *(const uint4*)(s_mem + rt_ + a0_ + j0b);         \
        R[st][5] = *(const uint4*)(s_mem + rt_ + a1_ + j1b);         \
        R[st][6] = *(const uint4*)(s_mem + rb_ + a0_ + j0b);         \
        R[st][7] = *(const uint4*)(s_mem + rb_ + a1_ + j1b);         \
    } while (0)

__global__ __launch_bounds__(512, 2) void fused_deform_v22(
        const unsigned short* __restrict__ xt,
        const unsigned short* __restrict__ wob_sw,
        const unsigned short* __restrict__ wkb_sw,
        const float* __restrict__ b_off, float* __restrict__ out) {
    extern __shared__ char s_mem[];                 // 156928 B dynamic
    const bf16x8* s_wv = (const bf16x8*)(s_mem + WREG);

    int gid  = blockIdx.x;                  // 512
    int xcd  = gid & 7;
    int j    = gid >> 3;
    int hh   = j & 15;
    int b    = j >> 4;
    int h    = xcd * 16 + hh;
    int tid  = threadIdx.x;
    int lane = tid & 63;
    int wave = __builtin_amdgcn_readfirstlane(tid >> 6);   // 0..7
    int l15  = lane & 15;
    int quad = lane >> 4;
    int p    = wave * 16 + l15;

    const unsigned short* xtb = xt + (size_t)b * HW * 64;

    // ---- stage x-window: 5 rows x 16 groups, padded dest, pre-swz source --
    int xl = lane >> 3;                     // pixel within 8-px group
    int sl = lane & 7;                      // dest 16B slot
    #pragma unroll
    for (int i = 0; i < 10; ++i) {
        int slot = i * 8 + wave;            // 0..79 (r,g) pairs
        int r  = slot >> 4;                 // 0..4
        int g  = slot & 15;                 // 0..15
        int y  = min(max(h - 2 + r, 0), Hn - 1);
        int xx = g * 8 + xl;
        int jj = sl ^ (xx & 7);             // pre-swizzled source chunk
        dma16(xtb + ((size_t)y * Wn + xx) * 64 + jj * 8,
              s_mem + (size_t)r * ROWB + (size_t)g * GRP);
    }
    // ---- stage wob into weight region ----
    #pragma unroll
    for (int i = 0; i < 5; ++i) {
        int seg = i * 8 + wave;
        if (seg < 36)
            dma16((const uint4*)wob_sw + seg * 64 + lane,
                  s_mem + WREG + (size_t)seg * 1024);
    }
    __syncthreads();                        // bar0: x-window + wob staged

    // ---- offset conv: 36 MFMA, B-operand from padded LDS window ----
    f32x4 oa0 = (f32x4){0.f, 0.f, 0.f, 0.f};
    f32x4 oa1 = (f32x4){0.f, 0.f, 0.f, 0.f};
    #pragma unroll
    for (int t9 = 0; t9 < 9; ++t9) {
        int ty = t9 / 3, tx = t9 % 3;
        int y  = h - 1 + ty;
        int xg = p - 1 + tx;
        bool v = (y >= 0) && (y < Hn) && (xg >= 0) && (xg < Wn);
        unsigned m = v ? 0xFFFFFFFFu : 0u;
        int yc = min(max(y, 0), Hn - 1);
        int xc = min(max(xg, 0), Wn - 1);
        int r  = yc - h + 2;                // always in [0,4]
        int base = r * ROWB + (xc >> 3) * GRP + (xc & 7) * 128;
        uint4 L0 = *(const uint4*)(s_mem + base + ((quad ^ (xc & 7)) << 4));
        uint4 L1 = *(const uint4*)(s_mem + base + (((4 + quad) ^ (xc & 7)) << 4));
        #pragma unroll
        for (int kc = 0; kc < 2; ++kc) {
            union { bf16x8 v; uint4 u; } bf;
            bf.u = kc ? L1 : L0;
            bf.u.x &= m; bf.u.y &= m; bf.u.z &= m; bf.u.w &= m;
            bf16x8 a0 = s_wv[((t9 * 2 + kc) * 2 + 0) * 64 + lane];
            bf16x8 a1 = s_wv[((t9 * 2 + kc) * 2 + 1) * 64 + lane];
            oa0 = __builtin_amdgcn_mfma_f32_16x16x32_bf16(a0, bf.v, oa0, 0, 0, 0);
            oa1 = __builtin_amdgcn_mfma_f32_16x16x32_bf16(a1, bf.v, oa1, 0, 0, 0);
        }
    }

    // ---- phase-1 (v13 verbatim) ----
    unsigned my_ad[3]  = {0, 0, 0};
    unsigned my_w01[3] = {0, 0, 0};
    unsigned my_w23[3] = {0, 0, 0};
    auto phase1 = [&](int k, float dy, float dx, int slot) {
        float py  = (float)(h - 1 + k / 3) + dy;
        float pxf = (float)(p - 1 + k % 3) + dx;
        float y0f = floorf(py), x0f = floorf(pxf);
        float fy = py - y0f, fx = pxf - x0f;
        int y0 = (int)y0f, x0 = (int)x0f;
        bool vy0 = (y0 >= 0) & (y0 < Hn);
        bool vy1 = (y0 + 1 >= 0) & (y0 + 1 < Hn);
        bool vx0 = (x0 >= 0) & (x0 < Wn);
        bool vx1 = (x0 + 1 >= 0) & (x0 + 1 < Wn);
        float wy0 = vy0 ? 1.f - fy : 0.f;
        float wy1 = vy1 ? fy : 0.f;
        float wx0 = vx0 ? 1.f - fx : 0.f;
        float wx1 = vx1 ? fx : 0.f;
        int xc = min(max(x0, 0), Wn - 2);
        bool sel0 = (min(max(x0, 0), Wn - 1) != xc);
        bool sel1 = ((min(max(x0 + 1, 0), Wn - 1) - xc) == 1);
        float Wa = (sel0 ? 0.f : wx0) + (sel1 ? 0.f : wx1);
        float Wb = (sel0 ? wx0 : 0.f) + (sel1 ? wx1 : 0.f);
        int yc0 = min(max(y0, 0), Hn - 1), yc1 = min(max(y0 + 1, 0), Hn - 1);
        union { __half2 hv; unsigned u; } c01, c23;
        c01.hv = __floats2half2_rn(wy0 * Wa, wy0 * Wb);
        c23.hv = __floats2half2_rn(wy1 * Wa, wy1 * Wb);
        my_ad[slot]  = (unsigned)yc0 | ((unsigned)yc1 << 8) | ((unsigned)xc << 16);
        my_w01[slot] = c01.u;
        my_w23[slot] = c23.u;
    };
    int kb = quad * 2;
    phase1(kb,     oa0[0] + b_off[4 * quad],     oa0[1] + b_off[4 * quad + 1], 0);
    phase1(kb + 1, oa0[2] + b_off[4 * quad + 2], oa0[3] + b_off[4 * quad + 3], 1);
    if (quad == 0)
        phase1(8, oa1[0] + b_off[16], oa1[1] + b_off[17], 2);
    __syncthreads();                        // bar1: wob LDS reads done

    // ---- stage wkb (72 segs) over wob region; shuffles cover flight ----
    #pragma unroll
    for (int i = 0; i < 9; ++i) {
        int seg = i * 8 + wave;
        dma16((const uint4*)wkb_sw + (size_t)seg * 64 + lane,
              s_mem + WREG + (size_t)seg * 1024);
    }

    unsigned ad[KKc], pw01[KKc], pw23[KKc];
    #pragma unroll
    for (int k = 0; k < KKc; ++k) {
        int src  = (k < 8) ? ((k >> 1) * 16 + l15) : l15;
        int slot = (k < 8) ? (k & 1) : 2;
        ad[k]   = (unsigned)__shfl((int)my_ad[slot],  src, 64);
        pw01[k] = (unsigned)__shfl((int)my_w01[slot], src, 64);
        pw23[k] = (unsigned)__shfl((int)my_w23[slot], src, 64);
    }
    __syncthreads();                        // bar2: wkb visible

    // ---- window test: all 9 taps' y-rows inside [h-2, h+2]? ----
    bool oow = false;
    #pragma unroll
    for (int k = 0; k < KKc; ++k) {
        int r0 = (int)(ad[k] & 255u) - h + 2;
        int r1 = (int)((ad[k] >> 8) & 255u) - h + 2;
        oow |= ((unsigned)r0 > 4u) | ((unsigned)r1 > 4u);
    }
    bool use_global = __any(oow);           // wave-uniform

    f32x4 acc[4];
    #pragma unroll
    for (int ot = 0; ot < 4; ++ot) acc[ot] = (f32x4){0.f, 0.f, 0.f, 0.f};

    uint4 R[2][8];
    int co0 = quad * 8, co1 = 32 + quad * 8;

    if (__builtin_expect(use_global, 0)) {
        FETCH_G(0, 0);
        FETCH_G(1, 1); TAP(0);
        FETCH_G(2, 0); TAP(1);
        FETCH_G(3, 1); TAP(2);
        FETCH_G(4, 0); TAP(3);
        FETCH_G(5, 1); TAP(4);
        FETCH_G(6, 0); TAP(5);
        FETCH_G(7, 1); TAP(6);
        FETCH_G(8, 0); TAP(7);
        TAP(8);
    } else {
        FETCH_L(0, 0);
        FETCH_L(1, 1); TAP(0);
        FETCH_L(2, 0); TAP(1);
        FETCH_L(3, 1); TAP(2);
        FETCH_L(4, 0); TAP(3);
        FETCH_L(5, 1); TAP(4);
        FETCH_L(6, 0); TAP(5);
        FETCH_L(7, 1); TAP(6);
        FETCH_L(8, 0); TAP(7);
        TAP(8);
    }

    #pragma unroll
    for (int ot = 0; ot < 4; ++ot)
        #pragma unroll
        for (int rr = 0; rr < 4; ++rr) {
            int o = ot * 16 + quad * 4 + rr;
            out[(((size_t)b * COUTc + o) * Hn + h) * Wn + p] = acc[ot][rr];
        }
}

// ---------------------------------------------------------------------------
extern "C" void kernel_launch(void* const* d_in, const int* in_sizes, int n_in,
                              void* d_out, int out_size, void* d_ws, size_t ws_size,
                              hipStream_t stream) {
    const float* x     = (const float*)d_in[0];
    const float* w_off = (const float*)d_in[1];
    const float* b_off = (const float*)d_in[2];
    const float* w_def = (const float*)d_in[3];
    float* out = (float*)d_out;

    char* ws = (char*)d_ws;
    unsigned short* xt = (unsigned short*)ws;                 // 8.39 MB
    ws += (size_t)Bn * HW * CINc * sizeof(unsigned short);
    unsigned short* wkb_sw = (unsigned short*)ws;             // 73728 B
    ws += 36864 * sizeof(unsigned short);
    unsigned short* wob_sw = (unsigned short*)ws;             // 36864 B

    static bool attr_set = false;
    if (!attr_set) {
        (void)hipFuncSetAttribute((const void*)fused_deform_v22,
                                  hipFuncAttributeMaxDynamicSharedMemorySize,
                                  156928);
        attr_set = true;
    }

    prep_all<<<256 + 216, 256, 0, stream>>>(x, xt, w_off, w_def, wkb_sw, wob_sw);
    fused_deform_v22<<<Bn * Hn, 512, 156928, stream>>>(xt, wob_sw, wkb_sw, b_off, out);
}